// Round 1
// 121.889 us; speedup vs baseline: 1.0115x; 1.0115x over previous
//
#include <hip/hip_runtime.h>

// B=4, S=1024, H=16, D=64 attention, clipped softmax.
// Round 9: r8 was pinned at ~72us for attn_stream because every wave of every
// block re-loads the same 8KB K/V chunk per 32-key step (512 blocks x 4 waves
// x 256KB = 512MB of redundant global traffic, served from L2/L3 at ~7TB/s).
// Fix: stage each 8KB step-chunk into LDS ONCE per block via global_load_lds
// (traffic /4), 4-slot ring + counted s_waitcnt vmcnt(4) (3 steps in flight,
// never drained mid-loop) + one s_barrier per step. LDS reads would be 8-way
// bank-conflicted in the linear image, so prep writes the workspace with an
// XOR swizzle (o ^= ((o>>7)&7)<<4 within each 1KB fragment); global_load_lds
// copies linearly; attn ds_reads with the same XOR -> conflict-free, and the
// MFMA operand values are bit-identical to r8.
//   kws2: [c32][frag 0..3][swz(n16*64+quad*16)]   (1 KB per (c32,frag))
//   vws2: [c32][dt 0..3]  [swz(quad*256+n16*16)]  (1 KB per (c32,dt))
#define BB 4
#define SS 1024
#define HH 16
#define DD 64

typedef short bf16x8 __attribute__((ext_vector_type(8)));
typedef float f32x4 __attribute__((ext_vector_type(4)));

__device__ __forceinline__ unsigned pk2(float a, float b) {   // pack 2 bf16
    unsigned ua = __float_as_uint(a) + 0x8000u;
    unsigned ub = __float_as_uint(b) + 0x8000u;
    return (ub & 0xffff0000u) | (ua >> 16);
}
__device__ __forceinline__ unsigned short f2bf(float a) {
    return (unsigned short)((__float_as_uint(a) + 0x8000u) >> 16);
}
__device__ __forceinline__ f32x4 mfma16(bf16x8 a, bf16x8 b, f32x4 c) {
    return __builtin_amdgcn_mfma_f32_16x16x32_bf16(a, b, c, 0, 0, 0);
}
// sigma within 32-key chunks (verified r4/r5): pos x holds key ((q^(b>>1))<<3)|(a<<2)|b
__device__ __forceinline__ int sig5(int x) {
    int a = (x >> 4) & 1, qs = (x >> 2) & 3, b2 = x & 3;
    return ((qs ^ (b2 >> 1)) << 3) | (a << 2) | b2;
}
// bank-conflict swizzle within a 1KB fragment: XOR bits 7..9 into bits 4..6.
// Bijective, 16B-alignment preserving. Applied at prep-write AND lds-read.
__device__ __forceinline__ unsigned swz1k(unsigned o) {
    return o ^ (((o >> 7) & 7u) << 4);
}

// ---------------- prep: K/V -> tiled-contiguous swizzled bf16 workspace ----------------
__global__ __launch_bounds__(256)
void prep_kernel(const float* __restrict__ k, const float* __restrict__ v,
                 unsigned short* __restrict__ kws, unsigned short* __restrict__ vws) {
    const int t = threadIdx.x;
    const int bx = blockIdx.x;
    if (bx < 512) {
        // K: thread handles permuted-position p = st*128 + row, d-half `half`
        const int bh = bx & 63, st = bx >> 6;
        const int h = bh & 15, b = bh >> 4;
        const int row = t >> 1, half = t & 1;
        const int p = st * 128 + row;
        const int key = (p & ~31) | sig5(p & 31);
        const float4* src = (const float4*)k + (((size_t)(b * SS + key) * HH + h) * 16) + half * 8;
        float4 r[8];
        #pragma unroll
        for (int i = 0; i < 8; ++i) r[i] = src[i];
        // dst: c32 = p/32, frag f = hi*2+half (hi = bit4 of row), lane n16 = p&15
        const int c32 = st * 4 + (row >> 5);
        const int f   = ((row >> 4) & 1) * 2 + half;
        const int n16k = row & 15;
        char* bp = (char*)(kws + (size_t)bh * 65536) + (size_t)((c32 * 4 + f) * 1024);
        #pragma unroll
        for (int u = 0; u < 4; ++u) {
            uint4 val;
            val.x = pk2(r[2*u].x, r[2*u].y);
            val.y = pk2(r[2*u].z, r[2*u].w);
            val.z = pk2(r[2*u+1].x, r[2*u+1].y);
            val.w = pk2(r[2*u+1].z, r[2*u+1].w);
            unsigned o = swz1k(((unsigned)n16k << 6) | ((unsigned)u << 4));
            *(uint4*)(bp + o) = val;
        }
    } else {
        // V: thread (o = key-octet 0..15, vc = d-group 0..15); no LDS needed.
        const int bx2 = bx - 512;
        const int bh = bx2 & 63, st = bx2 >> 6;
        const int h = bh & 15, b = bh >> 4;
        const int o = t >> 4, vc = t & 15;
        const float4* src = (const float4*)v + (((size_t)(b * SS + st * 128 + o * 8) * HH + h) * 16) + vc;
        float4 r[8];
        #pragma unroll
        for (int i = 0; i < 8; ++i) r[i] = src[(size_t)i * HH * 16];
        const float* fr = (const float*)r;
        const int c32 = st * 4 + (o >> 2);
        const int quad = o & 3;
        #pragma unroll
        for (int c = 0; c < 4; ++c) {
            const int d = 4 * vc + c;
            const int dt = d >> 4, n16v = d & 15;
            uint4 val;          // 8 keys (o*8..+7) at fixed d
            val.x = pk2(fr[0*4+c], fr[1*4+c]);
            val.y = pk2(fr[2*4+c], fr[3*4+c]);
            val.z = pk2(fr[4*4+c], fr[5*4+c]);
            val.w = pk2(fr[6*4+c], fr[7*4+c]);
            char* bp = (char*)(vws + (size_t)bh * 65536) + (size_t)((c32 * 4 + dt) * 1024);
            unsigned oo = swz1k(((unsigned)quad << 8) | ((unsigned)n16v << 4));
            *(uint4*)(bp + oo) = val;
        }
    }
}

// compute one 32-key step: QK^T -> exp -> PV (all in registers)
__device__ __forceinline__ void step32v(bf16x8 K0, bf16x8 K1, bf16x8 K2, bf16x8 K3,
                                        bf16x8 V0, bf16x8 V1, bf16x8 V2, bf16x8 V3,
                                        const bf16x8 qf[2][2],
                                        f32x4 oacc[2][4], float su[2]) {
    const f32x4 zero = {0.f, 0.f, 0.f, 0.f};
    const float LOG2E = 1.44269504f;
    f32x4 S[2][2];
    S[0][0] = mfma16(K1, qf[0][1], mfma16(K0, qf[0][0], zero));
    S[1][0] = mfma16(K1, qf[1][1], mfma16(K0, qf[1][0], zero));
    S[0][1] = mfma16(K3, qf[0][1], mfma16(K2, qf[0][0], zero));
    S[1][1] = mfma16(K3, qf[1][1], mfma16(K2, qf[1][0], zero));
    #pragma unroll
    for (int s = 0; s < 2; ++s) {
        unsigned P0[2], P1[2];
        #pragma unroll
        for (int ct = 0; ct < 2; ++ct) {
            float e0 = __builtin_amdgcn_exp2f(S[s][ct][0] * LOG2E);
            float e1 = __builtin_amdgcn_exp2f(S[s][ct][1] * LOG2E);
            float e2 = __builtin_amdgcn_exp2f(S[s][ct][2] * LOG2E);
            float e3 = __builtin_amdgcn_exp2f(S[s][ct][3] * LOG2E);
            su[s] += (e0 + e1) + (e2 + e3);
            P0[ct] = pk2(e0, e1);
            P1[ct] = pk2(e2, e3);
        }
        union { uint4 u; bf16x8 f; } pf;
        pf.u.x = P0[0];
        pf.u.y = (unsigned)__shfl_xor((int)P1[0], 16);
        pf.u.z = P0[1];
        pf.u.w = (unsigned)__shfl_xor((int)P1[1], 16);
        #pragma unroll
        for (int dt = 0; dt < 4; ++dt) {
            bf16x8 vv = dt == 0 ? V0 : dt == 1 ? V1 : dt == 2 ? V2 : V3;
            oacc[s][dt] = mfma16(vv, pf.f, oacc[s][dt]);
        }
    }
}

// ---------------- main: LDS-staged streaming attention ----------------
__global__ __launch_bounds__(256, 2)
void attn_stream(const float* __restrict__ q, const unsigned short* __restrict__ kws,
                 const unsigned short* __restrict__ vws, float* __restrict__ out) {
    // 4-slot ring, 8KB/slot: [0,4K) = K image (4 frags), [4K,8K) = V image
    __shared__ __align__(16) unsigned short ldsbuf[16384];   // 32 KB

    const int t = threadIdx.x, lane = t & 63, w = t >> 6;
    const int n16 = lane & 15, quad = lane >> 4;
    const int bx = blockIdx.x;               // 512 blocks
    const int bh = bx & 63, qt = bx >> 6;    // XCD swizzle: same bh -> same bx%8
    const int h = bh & 15, b = bh >> 4;
    const int qbase = qt * 128 + w * 32;

    // Q B-frags: q = sub*16+n16, d = ks*32+quad*8+j, pre-scaled 1/8
    bf16x8 qf[2][2];
    #pragma unroll
    for (int s = 0; s < 2; ++s)
      #pragma unroll
      for (int ks = 0; ks < 2; ++ks) {
        const float* p = q + (((size_t)(b * SS + qbase + s * 16 + n16) * HH + h) * DD)
                           + ks * 32 + quad * 8;
        float4 x = ((const float4*)p)[0];
        float4 y = ((const float4*)p)[1];
        bf16x8 f;
        f[0] = (short)f2bf(x.x * 0.125f); f[1] = (short)f2bf(x.y * 0.125f);
        f[2] = (short)f2bf(x.z * 0.125f); f[3] = (short)f2bf(x.w * 0.125f);
        f[4] = (short)f2bf(y.x * 0.125f); f[5] = (short)f2bf(y.y * 0.125f);
        f[6] = (short)f2bf(y.z * 0.125f); f[7] = (short)f2bf(y.w * 0.125f);
        qf[s][ks] = f;
      }

    const unsigned short* kb  = kws + (size_t)bh * 65536;
    const unsigned short* vbb = vws + (size_t)bh * 65536;

    f32x4 oacc[2][4];    // O^T: row d = dt*16+quad*4+r, col q = sub*16+n16
    #pragma unroll
    for (int s = 0; s < 2; ++s)
      #pragma unroll
      for (int dt = 0; dt < 4; ++dt) oacc[s][dt] = f32x4{0.f, 0.f, 0.f, 0.f};
    float su[2] = {0.f, 0.f};

    // per-lane swizzled byte offsets inside a 1KB fragment (match prep's swz1k)
    const unsigned basek = ((unsigned)n16 << 6) | ((unsigned)quad << 4);   // n16*64 + quad*16
    const unsigned basev = ((unsigned)quad << 8) | ((unsigned)n16 << 4);   // quad*256 + n16*16
    const unsigned okK = swz1k(basek);
    const unsigned okV = swz1k(basev);

    // staging: wave w copies K-frag w and V-frag w (1KB each, linear)
    const unsigned gsl = (unsigned)(w * 512 + lane * 8);   // shorts: frag base + lane*16B
    const unsigned lslK = (unsigned)(w * 512);             // wave-uniform LDS short offset
    const unsigned lslV = (unsigned)(2048 + w * 512);

#define STAGE(slot, chunk) do {                                                      \
    const unsigned short* gk_ = kb  + (unsigned)(chunk) * 2048u + gsl;               \
    const unsigned short* gv_ = vbb + (unsigned)(chunk) * 2048u + gsl;               \
    __builtin_amdgcn_global_load_lds(                                                \
        (const __attribute__((address_space(1))) void*)gk_,                          \
        (__attribute__((address_space(3))) void*)(ldsbuf + (slot) * 4096 + lslK),    \
        16, 0, 0);                                                                   \
    __builtin_amdgcn_global_load_lds(                                                \
        (const __attribute__((address_space(1))) void*)gv_,                          \
        (__attribute__((address_space(3))) void*)(ldsbuf + (slot) * 4096 + lslV),    \
        16, 0, 0);                                                                   \
} while (0)

    // prologue: 3 steps in flight (6 loads/wave outstanding in steady state)
    STAGE(0, 0); STAGE(1, 1); STAGE(2, 2);

    #pragma unroll 1
    for (int it = 0; it < 32; ++it) {
        // wait own stage(it) (2 newest steps = 4 loads may stay in flight),
        // then barrier -> all waves' stage(it) landed in LDS.
        asm volatile("s_waitcnt vmcnt(4)\n\ts_barrier" ::: "memory");
        // prefetch step it+3 into slot (it+3)&3 (= slot of it-1, all readers done).
        // Tail (it>=29) re-stages chunks 0..2 into dead slots: keeps vmcnt uniform.
        STAGE((it + 3) & 3, (it + 3) & 31);

        const char* sb = (const char*)ldsbuf + (it & 3) * 8192;
        bf16x8 K0 = *(const bf16x8*)(sb + okK);
        bf16x8 K1 = *(const bf16x8*)(sb + okK + 1024);
        bf16x8 K2 = *(const bf16x8*)(sb + okK + 2048);
        bf16x8 K3 = *(const bf16x8*)(sb + okK + 3072);
        bf16x8 V0 = *(const bf16x8*)(sb + okV + 4096);
        bf16x8 V1 = *(const bf16x8*)(sb + okV + 5120);
        bf16x8 V2 = *(const bf16x8*)(sb + okV + 6144);
        bf16x8 V3 = *(const bf16x8*)(sb + okV + 7168);
        step32v(K0, K1, K2, K3, V0, V1, V2, V3, qf, oacc, su);
    }
#undef STAGE
    // drain dummy stages before epilogue/endpgm
    asm volatile("s_waitcnt vmcnt(0)" ::: "memory");

    // epilogue: reduce su across quads (q lives on n16), normalize, store
    #pragma unroll
    for (int s = 0; s < 2; ++s) {
        su[s] += __shfl_xor(su[s], 16);
        su[s] += __shfl_xor(su[s], 32);
    }
    #pragma unroll
    for (int s = 0; s < 2; ++s) {
        float sc = 1.0f / su[s];     // clamps proven inactive; e^{-C'} cancels
        #pragma unroll
        for (int dt = 0; dt < 4; ++dt) {
            float4 val;
            val.x = oacc[s][dt][0] * sc;
            val.y = oacc[s][dt][1] * sc;
            val.z = oacc[s][dt][2] * sc;
            val.w = oacc[s][dt][3] * sc;
            size_t off = ((size_t)(b * SS + qbase + s * 16 + n16) * HH + h) * DD
                       + dt * 16 + quad * 4;
            *(float4*)&out[off] = val;
        }
    }
}

extern "C" void kernel_launch(void* const* d_in, const int* in_sizes, int n_in,
                              void* d_out, int out_size, void* d_ws, size_t ws_size,
                              hipStream_t stream) {
    const float* q = (const float*)d_in[0];
    const float* k = (const float*)d_in[1];
    const float* v = (const float*)d_in[2];
    float* o = (float*)d_out;
    unsigned short* kws = (unsigned short*)d_ws;                    // 8 MB
    unsigned short* vws = kws + (size_t)64 * 65536;                 // 8 MB
    hipLaunchKernelGGL(prep_kernel, dim3(1024), dim3(256), 0, stream, k, v, kws, vws);
    hipLaunchKernelGGL(attn_stream, dim3(512), dim3(256), 0, stream, q, kws, vws, o);
}